// Round 9
// baseline (157.880 us; speedup 1.0000x reference)
//
#include <hip/hip_runtime.h>
#include <hip/hip_bf16.h>

// GAT attention aggregator, fused. B=20000, N=32, D=128, H=256, O=128.
// R9: intra-block 2-tile software pipeline. 2500 blocks x 512 threads, each
// block processes 2 CONSECUTIVE MB=4 tiles (keeps L3 locality). Tile1 global
// loads issue before B1 (land during tile0 compute); tile1 LDS writes overlap
// final0 (neib region dead after agg0). bff (WcT panel) loaded once, reused
// by both finals. Final A-reads use a clamped 8-row base so LDS row ranges
// of final0 and the tile1 staging writes are disjoint (no extra barrier).

#define BB 20000
#define NN 32
#define DD 128
#define HH 256
#define OO 128
#define MB 4
#define ROWS 144     // 128 neib + x0(128..131) agg0(132..135) x1(136..139) agg1(140..143)
#define GRID 2500    // 2 tiles per block

typedef __bf16 bf16x8 __attribute__((ext_vector_type(8)));
typedef __bf16 bf16x4 __attribute__((ext_vector_type(4)));
typedef float f32x4 __attribute__((ext_vector_type(4)));

template<int CTRL>
__device__ __forceinline__ float dpp_add(float v) {
    int r = __builtin_amdgcn_update_dpp(0, __builtin_bit_cast(int, v), CTRL, 0xF, 0xF, true);
    return v + __builtin_bit_cast(float, r);
}
// lane 15 of each 16-lane row ends with the row sum
__device__ __forceinline__ float red16(float v) {
    v = dpp_add<0x111>(v);
    v = dpp_add<0x112>(v);
    v = dpp_add<0x114>(v);
    v = dpp_add<0x118>(v);
    return v;
}

__global__ void prep_weights(const float* __restrict__ Watt,
                             const float* __restrict__ Wfcx,
                             const float* __restrict__ Wfcn,
                             __bf16* __restrict__ WaT,
                             __bf16* __restrict__ WcT) {
    int idx = blockIdx.x * 256 + threadIdx.x;   // 0..65535
    int half = idx >> 15;
    int j = idx & 32767;
    int c = j >> 7, k = j & 127;
    if (half == 0) {
        WaT[j] = (__bf16)Watt[k * HH + c];       // WaT[h][k] = W_att[k][h]
    } else {
        float wv = (c < OO) ? Wfcx[k * OO + c] : Wfcn[k * OO + (c - OO)];
        WcT[j] = (__bf16)wv;                     // WcT[c][k]
    }
}

__launch_bounds__(512, 4)
__global__ void gat_fused(const float* __restrict__ x,
                          const float* __restrict__ neibs,
                          const float* __restrict__ a,
                          const __bf16* __restrict__ WaT,
                          const __bf16* __restrict__ WcT,
                          float* __restrict__ out) {
    __shared__ __bf16 rowsS[ROWS * 128];         // 36,864 B, XOR-swizzled rows
    __shared__ __bf16 e_part[8][ROWS];           //  2,304 B

    const int tid = threadIdx.x;
    const int w   = tid >> 6;      // wave 0..7
    const int l   = tid & 63;
    const int lr  = l & 15;
    const int lg  = l >> 4;
    char* rbase = (char*)rowsS;

    // staging: float4 idx = it*512 + tid; row = it*16 + (tid>>5)
    const int s = tid >> 5;                       // 0..15; row&7 = s&7
    const int stbase = s * 256 + ((8 * (tid & 31)) ^ ((s & 7) << 4));
    const int lrc = lr & 7;                       // clamped A-row for finals
    int abase[4], fbase[4];
#pragma unroll
    for (int ks = 0; ks < 4; ++ks) {
        abase[ks] = lr * 256 + ((ks * 64 + lg * 16) ^ ((lr & 7) << 4));
        fbase[ks] = lrc * 256 + ((ks * 64 + lg * 16) ^ (lrc << 4));
    }
    float aX[2], aN[2];
#pragma unroll
    for (int c4 = 0; c4 < 2; ++c4) {
        int col = (w * 2 + c4) * 16 + lr;
        aX[c4] = a[col];
        aN[c4] = a[HH + col];
    }
    const int node = w & 3;
    const int nl = l & 31;

    const int g0 = (int)blockIdx.x * 2;
    const float4* np4 = (const float4*)neibs + (size_t)g0 * 4096;
    const float4* xp4 = (const float4*)x + (size_t)g0 * 128;

    // ---- stage tile0 (two-phase) ----
    {
        float4 nv[8];
#pragma unroll
        for (int it = 0; it < 8; ++it) nv[it] = np4[it * 512 + tid];
        float4 xv;
        if (tid < 128) xv = xp4[tid];
#pragma unroll
        for (int it = 0; it < 8; ++it) {
            bf16x4 sv = { (__bf16)nv[it].x, (__bf16)nv[it].y, (__bf16)nv[it].z, (__bf16)nv[it].w };
            *(bf16x4*)(rbase + stbase + it * 4096) = sv;
        }
        if (tid < 128) {                          // x0 rows 128..131
            bf16x4 sv = { (__bf16)xv.x, (__bf16)xv.y, (__bf16)xv.z, (__bf16)xv.w };
            *(bf16x4*)(rbase + stbase + 32768) = sv;
        }
    }

    // W_att panel for score0 (L2-resident)
    bf16x8 bw[2][4];
#pragma unroll
    for (int c4 = 0; c4 < 2; ++c4)
#pragma unroll
        for (int ks = 0; ks < 4; ++ks)
            bw[c4][ks] = *(const bf16x8*)(WaT + ((w * 2 + c4) * 16 + lr) * 128 + ks * 32 + lg * 8);

    // ---- prefetch tile1 (lands during tile0 compute) ----
    float4 nv1[8], xv1;
#pragma unroll
    for (int it = 0; it < 8; ++it) nv1[it] = np4[4096 + it * 512 + tid];
    if (tid < 128) xv1 = xp4[128 + tid];

    // score: [neib 8 tiles + x tile] @ WaT^T, fused lrelu(.01)*a + DPP reduce
    auto SCORE = [&]() {
#pragma unroll 2
        for (int rt = 0; rt < 9; ++rt) {
            const int off = (rt < 8) ? rt * 4096 : 32768;
            bf16x8 af[4];
#pragma unroll
            for (int ks = 0; ks < 4; ++ks)
                af[ks] = *(const bf16x8*)(rbase + abase[ks] + off);
            f32x4 acc[2];
            acc[0] = (f32x4){0.f, 0.f, 0.f, 0.f};
            acc[1] = (f32x4){0.f, 0.f, 0.f, 0.f};
#pragma unroll
            for (int ks = 0; ks < 4; ++ks)
#pragma unroll
                for (int c4 = 0; c4 < 2; ++c4)
                    acc[c4] = __builtin_amdgcn_mfma_f32_16x16x32_bf16(af[ks], bw[c4][ks], acc[c4], 0, 0, 0);
            float ep[4] = {0.f, 0.f, 0.f, 0.f};
#pragma unroll
            for (int c4 = 0; c4 < 2; ++c4) {
                float av = (rt == 8) ? aX[c4] : aN[c4];
#pragma unroll
                for (int i = 0; i < 4; ++i) {
                    float v = acc[c4][i];
                    float lv = fmaxf(v, 0.f) + 0.01f * fminf(v, 0.f);
                    ep[i] = fmaf(lv, av, ep[i]);
                }
            }
#pragma unroll
            for (int i = 0; i < 4; ++i) ep[i] = red16(ep[i]);
            if (lr == 15) {
                bf16x4 st = { (__bf16)ep[0], (__bf16)ep[1], (__bf16)ep[2], (__bf16)ep[3] };
                *(bf16x4*)((char*)e_part + w * (2 * ROWS) + rt * 32 + lg * 8) = st;
            }
        }
    };

    auto SOFTMAX = [&](int xr) -> float {
        const int idx = node * 32 + nl;
        float e = 0.f;
#pragma unroll
        for (int wv = 0; wv < 8; ++wv)
            e += (float)e_part[wv][idx] + (float)e_part[wv][xr];
        e = (e > 0.f) ? e : 0.2f * e;
        float mx = e;
#pragma unroll
        for (int m = 16; m >= 1; m >>= 1) mx = fmaxf(mx, __shfl_xor(mx, m, 32));
        float ex = __expf(e - mx);
        float sum = ex;
#pragma unroll
        for (int m = 16; m >= 1; m >>= 1) sum += __shfl_xor(sum, m, 32);
        return ex / sum;
    };

    auto AGG = [&](float att, int aggrow) {       // one (node,d) element per thread
        const int d = ((w >> 2) << 6) + l;        // 0..127
        const int agb = node * 8192 + 2 * d;
        float ag = 0.f;
#pragma unroll
        for (int n = 0; n < 32; ++n) {
            float wv = __shfl(att, n);
            __bf16 v = *(const __bf16*)(rbase + ((agb + n * 256) ^ ((n & 7) << 4)));
            ag = fmaf(wv, (float)v, ag);
        }
        int off = aggrow * 256 + ((2 * d) ^ ((aggrow & 7) << 4));
        *(__bf16*)(rbase + off) = (__bf16)ag;
    };

    auto FINAL = [&](int slotoff, int b0, bf16x8 (&bf)[2][4]) {
        bf16x8 af[4];
#pragma unroll
        for (int ks = 0; ks < 4; ++ks)
            af[ks] = *(const bf16x8*)(rbase + fbase[ks] + slotoff);  // rows slot..slot+7
        f32x4 acc[2];
        acc[0] = (f32x4){0.f, 0.f, 0.f, 0.f};
        acc[1] = (f32x4){0.f, 0.f, 0.f, 0.f};
#pragma unroll
        for (int ks = 0; ks < 4; ++ks)
#pragma unroll
            for (int c4 = 0; c4 < 2; ++c4)
                acc[c4] = __builtin_amdgcn_mfma_f32_16x16x32_bf16(af[ks], bf[c4][ks], acc[c4], 0, 0, 0);
#pragma unroll
        for (int c4 = 0; c4 < 2; ++c4) {
            int col = (w * 2 + c4) * 16 + lr;
#pragma unroll
            for (int reg = 0; reg < 4; ++reg) {
                int i = lg * 4 + reg;             // C row: 0..3 = x, 4..7 = agg
                bool doit = (col < 128) ? (i < 4) : (i >= 4 && i < 8);
                if (doit) out[(size_t)(b0 + (i & 3)) * 256 + col] = fmaxf(acc[c4][reg], 0.f);
            }
        }
    };

    __syncthreads();                              // B1: tile0 staged
    SCORE();                                      // tile0 scores
    __syncthreads();                              // B2
    float att0 = SOFTMAX(128 + node);
    bf16x8 bff[2][4];                             // WcT panel: reused by both finals
#pragma unroll
    for (int c4 = 0; c4 < 2; ++c4)
#pragma unroll
        for (int ks = 0; ks < 4; ++ks)
            bff[c4][ks] = *(const bf16x8*)(WcT + ((w * 2 + c4) * 16 + lr) * 128 + ks * 32 + lg * 8);
    AGG(att0, 132 + node);                        // agg0 -> rows 132..135
    __syncthreads();                              // B3: agg0 visible; neib region dead
    FINAL(32768, g0 * MB, bff);                   // reads rows 128..135 only
    // stage tile1 from regs (rows 0..127 + x1 rows 136..139; disjoint from FINAL0 reads)
#pragma unroll
    for (int it = 0; it < 8; ++it) {
        bf16x4 sv = { (__bf16)nv1[it].x, (__bf16)nv1[it].y, (__bf16)nv1[it].z, (__bf16)nv1[it].w };
        *(bf16x4*)(rbase + stbase + it * 4096) = sv;
    }
    if (tid < 128) {
        bf16x4 sv = { (__bf16)xv1.x, (__bf16)xv1.y, (__bf16)xv1.z, (__bf16)xv1.w };
        *(bf16x4*)(rbase + stbase + 34816) = sv;  // x1 rows 136..139
    }
    // reload W_att panel for score1 (L2 hit, hidden under staging writes)
#pragma unroll
    for (int c4 = 0; c4 < 2; ++c4)
#pragma unroll
        for (int ks = 0; ks < 4; ++ks)
            bw[c4][ks] = *(const bf16x8*)(WaT + ((w * 2 + c4) * 16 + lr) * 128 + ks * 32 + lg * 8);
    __syncthreads();                              // B4: tile1 staged
    SCORE();                                      // tile1 scores (x1 at rows 136..139)
    __syncthreads();                              // B5
    float att1 = SOFTMAX(136 + node);
    AGG(att1, 140 + node);                        // agg1 -> rows 140..143
    __syncthreads();                              // B6
    FINAL(34816, g0 * MB + MB, bff);              // reads rows 136..143
}

extern "C" void kernel_launch(void* const* d_in, const int* in_sizes, int n_in,
                              void* d_out, int out_size, void* d_ws, size_t ws_size,
                              hipStream_t stream) {
    const float* x    = (const float*)d_in[0];
    const float* nb   = (const float*)d_in[1];
    const float* Watt = (const float*)d_in[2];
    const float* Wfcx = (const float*)d_in[3];
    const float* Wfcn = (const float*)d_in[4];
    const float* a    = (const float*)d_in[5];
    __bf16* WaT = (__bf16*)d_ws;
    __bf16* WcT = WaT + 128 * 256;
    float* o = (float*)d_out;

    prep_weights<<<256, 256, 0, stream>>>(Watt, Wfcx, Wfcn, WaT, WcT);
    gat_fused<<<GRID, 512, 0, stream>>>(x, nb, a, WaT, WcT, o);
}

// Round 10
// 155.976 us; speedup vs baseline: 1.0122x; 1.0122x over previous
//
#include <hip/hip_runtime.h>
#include <hip/hip_bf16.h>

// GAT attention aggregator. B=20000, N=32, D=128, H=256, O=128.
// R10: cross-tile pipeline. prep_weights (bf16 transposed W) + prep_x
// (x@Wfcx -> out[:, :128] and e_x = lrelu(x@Watt).a[:H]) + gat_main:
// 1000 blocks x 512 thr, 5 consecutive MB=4 tiles each. Per tile, next
// tile's global loads are issued before score and stay IN FLIGHT across
// raw lgkmcnt-only barriers (hipcc's __syncthreads drains vmcnt -> would
// kill the overlap). Stage-writes go to the wave-private (row,col-half)
// region the same wave just agg-read. 2 barriers/tile.

#define BB 20000
#define NN 32
#define DD 128
#define HH 256
#define OO 128

typedef __bf16 bf16x8 __attribute__((ext_vector_type(8)));
typedef __bf16 bf16x4 __attribute__((ext_vector_type(4)));
typedef float f32x4 __attribute__((ext_vector_type(4)));

#define LBAR() do { asm volatile("s_waitcnt lgkmcnt(0)" ::: "memory"); \
                    __builtin_amdgcn_s_barrier(); } while (0)

template<int CTRL>
__device__ __forceinline__ float dpp_add(float v) {
    int r = __builtin_amdgcn_update_dpp(0, __builtin_bit_cast(int, v), CTRL, 0xF, 0xF, true);
    return v + __builtin_bit_cast(float, r);
}
// lane 15 of each 16-lane row ends with the row sum
__device__ __forceinline__ float red16(float v) {
    v = dpp_add<0x111>(v);
    v = dpp_add<0x112>(v);
    v = dpp_add<0x114>(v);
    v = dpp_add<0x118>(v);
    return v;
}

__global__ void prep_weights(const float* __restrict__ Watt,
                             const float* __restrict__ Wfcx,
                             const float* __restrict__ Wfcn,
                             __bf16* __restrict__ WaT,
                             __bf16* __restrict__ WcT) {
    int idx = blockIdx.x * 256 + threadIdx.x;   // 0..65535
    int half = idx >> 15;
    int j = idx & 32767;
    int c = j >> 7, k = j & 127;
    if (half == 0) {
        WaT[j] = (__bf16)Watt[k * HH + c];       // WaT[h][k] = W_att[k][h]
    } else {
        float wv = (c < OO) ? Wfcx[k * OO + c] : Wfcn[k * OO + (c - OO)];
        WcT[j] = (__bf16)wv;                     // WcT[c][k]
    }
}

// out[:, :128] = relu(x@Wfcx);  e_x[b] = sum_h lrelu01(x@Watt)[b,h]*a[h]
__launch_bounds__(256, 4)
__global__ void prep_x(const float* __restrict__ x,
                       const float* __restrict__ a,
                       const __bf16* __restrict__ WaT,
                       const __bf16* __restrict__ WcT,
                       float* __restrict__ out,
                       float* __restrict__ e_x) {
    __shared__ __bf16 xs[32 * 128];              // swizzled x rows
    __shared__ float esc[4][32];
    const int tid = threadIdx.x;
    const int w = tid >> 6, l = tid & 63, lr = l & 15, lg = l >> 4;
    const int r0 = blockIdx.x * 32;
    char* xb = (char*)xs;

    {   // stage 32 x-rows as bf16
        int row = tid >> 3, fb = (tid & 7) * 4;  // 8 thr/row, 4 float4 each
        const float4* xp4 = (const float4*)x + (size_t)r0 * 32;
        float4 v0 = xp4[row * 32 + fb + 0], v1 = xp4[row * 32 + fb + 1];
        float4 v2 = xp4[row * 32 + fb + 2], v3 = xp4[row * 32 + fb + 3];
        bf16x8 s0 = { (__bf16)v0.x,(__bf16)v0.y,(__bf16)v0.z,(__bf16)v0.w,
                      (__bf16)v1.x,(__bf16)v1.y,(__bf16)v1.z,(__bf16)v1.w };
        bf16x8 s1 = { (__bf16)v2.x,(__bf16)v2.y,(__bf16)v2.z,(__bf16)v2.w,
                      (__bf16)v3.x,(__bf16)v3.y,(__bf16)v3.z,(__bf16)v3.w };
        *(bf16x8*)(xb + ((row * 256 + fb * 8)      ^ ((row & 7) << 4))) = s0;
        *(bf16x8*)(xb + ((row * 256 + fb * 8 + 16) ^ ((row & 7) << 4))) = s1;
    }
    __syncthreads();

    int abase[4];
#pragma unroll
    for (int ks = 0; ks < 4; ++ks)
        abase[ks] = lr * 256 + ((ks * 64 + lg * 16) ^ ((lr & 7) << 4));
    bf16x8 af[2][4];
#pragma unroll
    for (int rt = 0; rt < 2; ++rt)
#pragma unroll
        for (int ks = 0; ks < 4; ++ks)
            af[rt][ks] = *(const bf16x8*)(xb + abase[ks] + rt * 4096);

    float ep[2][4] = {{0.f,0.f,0.f,0.f},{0.f,0.f,0.f,0.f}};
#pragma unroll
    for (int cc = 0; cc < 6; ++cc) {
        const int ct = w + 4 * cc;               // 24 col-tiles: 0..7 Wfcx, 8..23 Watt
        const int col = ct * 16 + lr;
        const __bf16* bs = (ct < 8) ? (WcT + (size_t)col * 128)
                                    : (WaT + (size_t)(col - 128) * 128);
        bf16x8 bw[4];
#pragma unroll
        for (int ks = 0; ks < 4; ++ks)
            bw[ks] = *(const bf16x8*)(bs + ks * 32 + lg * 8);
#pragma unroll
        for (int rt = 0; rt < 2; ++rt) {
            f32x4 acc = (f32x4){0.f, 0.f, 0.f, 0.f};
#pragma unroll
            for (int ks = 0; ks < 4; ++ks)
                acc = __builtin_amdgcn_mfma_f32_16x16x32_bf16(af[rt][ks], bw[ks], acc, 0, 0, 0);
            if (ct < 8) {
#pragma unroll
                for (int i = 0; i < 4; ++i)
                    out[(size_t)(r0 + rt * 16 + 4 * lg + i) * 256 + col] = fmaxf(acc[i], 0.f);
            } else {
                float av = a[col - 128];
#pragma unroll
                for (int i = 0; i < 4; ++i) {
                    float vv = acc[i];
                    float lv = fmaxf(vv, 0.f) + 0.01f * fminf(vv, 0.f);
                    ep[rt][i] = fmaf(lv, av, ep[rt][i]);
                }
            }
        }
    }
#pragma unroll
    for (int rt = 0; rt < 2; ++rt)
#pragma unroll
        for (int i = 0; i < 4; ++i) ep[rt][i] = red16(ep[rt][i]);
    if (lr == 15)
#pragma unroll
        for (int rt = 0; rt < 2; ++rt)
#pragma unroll
            for (int i = 0; i < 4; ++i)
                esc[w][rt * 16 + 4 * lg + i] = ep[rt][i];
    __syncthreads();
    if (tid < 32)
        e_x[r0 + tid] = esc[0][tid] + esc[1][tid] + esc[2][tid] + esc[3][tid];
}

__launch_bounds__(512, 4)
__global__ void gat_main(const float* __restrict__ neibs,
                         const float* __restrict__ a,
                         const __bf16* __restrict__ WaT,
                         const __bf16* __restrict__ WcT,
                         const float* __restrict__ e_x,
                         float* __restrict__ out) {
    __shared__ __bf16 rowsS[128 * 128];          // 32 KB neib quadrants, swizzled
    __shared__ __bf16 aggA[16 * 128];            //  4 KB final A-tile (rows 0..3 agg)
    __shared__ __bf16 e2[128][8];                //  2 KB e-partials [row][wave]

    const int tid = threadIdx.x;
    const int w  = tid >> 6;                     // wave 0..7
    const int l  = tid & 63;
    const int lr = l & 15;
    const int lg = l >> 4;
    const int q  = w & 3;                        // local node owned by this wave pair
    const int dh = w >> 2;                       // d-half (0: d<64, 1: d>=64)
    char* rb = (char*)rowsS;
    char* ab = (char*)aggA;

    int abase[4];
#pragma unroll
    for (int ks = 0; ks < 4; ++ks)
        abase[ks] = lr * 256 + ((ks * 64 + lg * 16) ^ ((lr & 7) << 4));

    // staging geometry: lane stages row 32q+(l>>1), byte-cols dh*128+(l&1)*64 .. +63
    const int srow = 32 * q + (l >> 1);
    const int scol = dh * 128 + (l & 1) * 64;
    const size_t sg4 = (size_t)srow * 32 + dh * 16 + (l & 1) * 8;  // float4 idx in tile

    // resident B panels
    bf16x8 bw[2][4];
    float aN[2];
#pragma unroll
    for (int c4 = 0; c4 < 2; ++c4) {
        int col = (w * 2 + c4) * 16 + lr;
#pragma unroll
        for (int ks = 0; ks < 4; ++ks)
            bw[c4][ks] = *(const bf16x8*)(WaT + (size_t)col * 128 + ks * 32 + lg * 8);
        aN[c4] = a[HH + col];
    }
    bf16x8 bff[4];
    {
        int colf = 128 + w * 16 + lr;            // WcT rows 128..255 = Wfcn^T
#pragma unroll
        for (int ks = 0; ks < 4; ++ks)
            bff[ks] = *(const bf16x8*)(WcT + (size_t)colf * 128 + ks * 32 + lg * 8);
    }

    const float4* np4 = (const float4*)neibs;
    float4 pf[8];
    auto STAGE_WRITE = [&]() {
#pragma unroll
        for (int k = 0; k < 4; ++k) {
            float4 u = pf[2 * k], v = pf[2 * k + 1];
            bf16x8 s = { (__bf16)u.x,(__bf16)u.y,(__bf16)u.z,(__bf16)u.w,
                         (__bf16)v.x,(__bf16)v.y,(__bf16)v.z,(__bf16)v.w };
            *(bf16x8*)(rb + ((srow * 256 + scol + k * 16) ^ ((srow & 7) << 4))) = s;
        }
    };

    int g0 = (int)blockIdx.x * 20;               // 5 tiles x 4 nodes

    // prologue: stage tile 0
    {
        size_t tb = (size_t)g0 * 1024 + sg4;
#pragma unroll
        for (int i = 0; i < 8; ++i) pf[i] = np4[tb + i];
        STAGE_WRITE();
    }
    __syncthreads();

#pragma unroll 1
    for (int t = 0; t < 5; ++t, g0 += 4) {
        float exv = e_x[g0 + q];
        // issue next tile's loads: stay in flight across the lgkm-only barriers
        if (t < 4) {
            size_t tb = (size_t)(g0 + 4) * 1024 + sg4;
#pragma unroll
            for (int i = 0; i < 8; ++i) pf[i] = np4[tb + i];
        }

        // ---- score: [128x128] @ WaT^T (own 32 h-cols), lrelu(.01)*a, DPP reduce ----
#pragma unroll
        for (int rt = 0; rt < 8; ++rt) {
            bf16x8 af[4];
#pragma unroll
            for (int ks = 0; ks < 4; ++ks)
                af[ks] = *(const bf16x8*)(rb + abase[ks] + rt * 4096);
            f32x4 acc[2];
            acc[0] = (f32x4){0.f,0.f,0.f,0.f};
            acc[1] = (f32x4){0.f,0.f,0.f,0.f};
#pragma unroll
            for (int ks = 0; ks < 4; ++ks)
#pragma unroll
                for (int c4 = 0; c4 < 2; ++c4)
                    acc[c4] = __builtin_amdgcn_mfma_f32_16x16x32_bf16(af[ks], bw[c4][ks], acc[c4], 0, 0, 0);
            float ep[4] = {0.f, 0.f, 0.f, 0.f};
#pragma unroll
            for (int c4 = 0; c4 < 2; ++c4)
#pragma unroll
                for (int i = 0; i < 4; ++i) {
                    float v = acc[c4][i];
                    float lv = fmaxf(v, 0.f) + 0.01f * fminf(v, 0.f);
                    ep[i] = fmaf(lv, aN[c4], ep[i]);
                }
#pragma unroll
            for (int i = 0; i < 4; ++i) ep[i] = red16(ep[i]);
            if (lr == 15)
#pragma unroll
                for (int i = 0; i < 4; ++i)
                    e2[rt * 16 + 4 * lg + i][w] = (__bf16)ep[i];
        }
        LBAR();                                   // B2: e2 visible; score reads done

        // ---- softmax over 32 neighbors (in-wave; halves duplicate) ----
        float att;
        {
            const int nl = l & 31;
            bf16x8 ev = *(const bf16x8*)(&e2[q * 32 + nl][0]);
            float e = exv;
#pragma unroll
            for (int j = 0; j < 8; ++j) e += (float)ev[j];
            e = (e > 0.f) ? e : 0.2f * e;
            float mx = e;
#pragma unroll
            for (int m = 16; m >= 1; m >>= 1) mx = fmaxf(mx, __shfl_xor(mx, m, 32));
            float ex = __expf(e - mx);
            float sum = ex;
#pragma unroll
            for (int m = 16; m >= 1; m >>= 1) sum += __shfl_xor(sum, m, 32);
            att = ex / sum;
        }

        // ---- agg: lane = (d-quad dq, n-group ngrp); reads own (rows, d-half) ----
        const int dq = l & 15, ngrp = l >> 4;
        float ag[4] = {0.f, 0.f, 0.f, 0.f};
#pragma unroll
        for (int j = 0; j < 8; ++j) {
            int n = ngrp + 4 * j;
            float wv = __shfl(att, n);
            int row = 32 * q + n;
            bf16x4 vv = *(const bf16x4*)(rb + ((row * 256 + dh * 128 + dq * 8) ^ ((row & 7) << 4)));
#pragma unroll
            for (int c = 0; c < 4; ++c) ag[c] = fmaf(wv, (float)vv[c], ag[c]);
        }
#pragma unroll
        for (int c = 0; c < 4; ++c) {
            ag[c] += __shfl_xor(ag[c], 16);
            ag[c] += __shfl_xor(ag[c], 32);
        }

        // ---- stage-write t+1 into own (rows, d-half) region (just agg-read) ----
        if (t < 4) STAGE_WRITE();

        // ---- agg row -> final A-tile ----
        if (ngrp == 0) {
            bf16x4 s = { (__bf16)ag[0], (__bf16)ag[1], (__bf16)ag[2], (__bf16)ag[3] };
            *(bf16x4*)(ab + ((q * 256 + dh * 128 + dq * 8) ^ ((q & 7) << 4))) = s;
        }
        LBAR();                                   // B3: staged rows + agg rows visible

        // ---- final: [agg;junk](16x128) @ Wfcn^T slice (16 cols/wave), cols 128+ ----
        {
            bf16x8 aff[4];
#pragma unroll
            for (int ks = 0; ks < 4; ++ks)
                aff[ks] = *(const bf16x8*)(ab + abase[ks]);
            f32x4 accf = (f32x4){0.f, 0.f, 0.f, 0.f};
#pragma unroll
            for (int ks = 0; ks < 4; ++ks)
                accf = __builtin_amdgcn_mfma_f32_16x16x32_bf16(aff[ks], bff[ks], accf, 0, 0, 0);
            if (lg == 0) {
#pragma unroll
                for (int reg = 0; reg < 4; ++reg)
                    out[(size_t)(g0 + reg) * 256 + 128 + w * 16 + lr] = fmaxf(accf[reg], 0.f);
            }
        }
    }
}

extern "C" void kernel_launch(void* const* d_in, const int* in_sizes, int n_in,
                              void* d_out, int out_size, void* d_ws, size_t ws_size,
                              hipStream_t stream) {
    const float* x    = (const float*)d_in[0];
    const float* nb   = (const float*)d_in[1];
    const float* Watt = (const float*)d_in[2];
    const float* Wfcx = (const float*)d_in[3];
    const float* Wfcn = (const float*)d_in[4];
    const float* a    = (const float*)d_in[5];
    __bf16* WaT = (__bf16*)d_ws;
    __bf16* WcT = WaT + 32768;
    float*  e_x = (float*)(WcT + 32768);
    float*  o   = (float*)d_out;

    prep_weights<<<256, 256, 0, stream>>>(Watt, Wfcx, Wfcn, WaT, WcT);
    prep_x<<<625, 256, 0, stream>>>(x, a, WaT, WcT, o, e_x);
    gat_main<<<1000, 512, 0, stream>>>(nb, a, WaT, WcT, e_x, o);
}